// Round 7
// baseline (226.198 us; speedup 1.0000x reference)
//
#include <hip/hip_runtime.h>
#include <hip/hip_bf16.h>

// Problem constants
#define C_   32
#define S_   20
#define V_   8000     // 20^3
#define K3_  125
#define OC_  375      // 3*K3
#define NP_  384      // padded N
#define KK_  4000     // 32*125

// Workspace layout (float offsets). Peak 2.704M floats = 10.82 MB (unchanged).
#define WS_ATTN1T 0                        // fp32 [v][c]          256000
#define WS_XT     256000                   // f16  [v][c]          128000 fl
#define WS_WDWT   384000                   // fp32 [k][c]            4000
#define WS_WSPT   388000                   // fp32 [k][c]           10976
#define WS_WPWT   398976                   // fp32 [c][o]            1024
#define WS_OFFB   400000                   // f16  [v][384]       1536000 fl
#define WS_BPREP  1936000                  // f16 [n][k] 768000 fl; dead after gemm
#define WS_XP     1936000                  //   -> reused: half2 [v][c] 256000 fl
#define WS_ATTN2T 2192000                  //   -> reused: fp32 [v][c] 256000 fl
// Zero page: first 16 floats of ATTN1T region (dead until deform_kernel).
#define WS_ZERO   WS_ATTN1T

typedef __attribute__((ext_vector_type(8))) short bf16x8;
typedef __attribute__((ext_vector_type(4))) float f32x4;
typedef __fp16 h2_t __attribute__((ext_vector_type(2)));   // matches builtins

static __device__ __forceinline__ unsigned short f2h(float f) {
    _Float16 h = (_Float16)f;
    return __builtin_bit_cast(unsigned short, h);
}
static __device__ __forceinline__ float h2f(unsigned short b) {
    return (float)__builtin_bit_cast(_Float16, b);
}
static __device__ __forceinline__ h2_t bch2(unsigned u) {
    return __builtin_bit_cast(h2_t, u);
}
static __device__ __forceinline__ unsigned pkh2(float a, float b) {
#if __has_builtin(__builtin_amdgcn_cvt_pkrtz)
    return __builtin_bit_cast(unsigned, __builtin_amdgcn_cvt_pkrtz(a, b));
#else
    return (unsigned)f2h(a) | ((unsigned)f2h(b) << 16);
#endif
}
static __device__ __forceinline__ float dot2(unsigned xu, unsigned wu, float c) {
#if __has_builtin(__builtin_amdgcn_fdot2)
    return __builtin_amdgcn_fdot2(bch2(xu), bch2(wu), c, false);
#else
    h2_t xh = bch2(xu), wh = bch2(wu);
    return c + (float)xh[0] * (float)wh[0] + (float)xh[1] * (float)wh[1];
#endif
}

// ---------------------------------------------------------------------------
// Transposes: xt[v][c] f16; wdwT[k][c]; wspT[k][c]; wpwT[c][o] (fp32).
// Also zeroes the 64B zero page used by gemm's OOB lane redirect.
// ---------------------------------------------------------------------------
__global__ __launch_bounds__(256) void transpose_kernel(
    const float* __restrict__ x,
    const float* __restrict__ w_dw,
    const float* __restrict__ w_sp,
    const float* __restrict__ w_pw,
    unsigned short* __restrict__ xt,
    float* __restrict__ wdwT,
    float* __restrict__ wspT,
    float* __restrict__ wpwT,
    float* __restrict__ zpage)
{
    int i = blockIdx.x * 256 + threadIdx.x;
    if (i < 256000) {
        int v = i >> 5, c = i & 31;
        xt[i] = f2h(x[c * V_ + v]);
        return;
    }
    int j = i - 256000;
    if (j < 4000)  { wdwT[j] = w_dw[(j & 31) * K3_ + (j >> 5)]; return; }
    j -= 4000;
    if (j < 10976) { wspT[j] = w_sp[(j & 31) * 343 + (j >> 5)]; return; }
    j -= 10976;
    if (j < 1024)  { wpwT[j] = w_pw[(j & 31) * 32 + (j >> 5)]; return; }
    j -= 1024;
    if (j < 16)    { zpage[j] = 0.f; return; }
}

// ---------------------------------------------------------------------------
// Weight transform: Bprep[n][k] f16, k = tap*32 + c; n >= 375 zeroed.
// ---------------------------------------------------------------------------
__global__ __launch_bounds__(256) void prep_b_kernel(
    const float* __restrict__ w_off, unsigned short* __restrict__ Bprep)
{
    int idx = blockIdx.x * 256 + threadIdx.x;
    if (idx >= NP_ * KK_) return;
    int n = idx / KK_, r = idx % KK_;
    int tap = r >> 5, c = r & 31;
    float v = (n < OC_) ? w_off[n * KK_ + c * K3_ + tap] : 0.f;
    Bprep[idx] = f2h(v);
}

// ---------------------------------------------------------------------------
// Offset conv as implicit-GEMM MFMA (f16): D[8000][384] = A[8000][4000]*B.
// Tile 64x64, BK=64 (2 taps/iter), 4 waves 2x2, wave tile 32x32.
// R4 2-phase structure (verified best: occupancy is the latency hider) with
// ONE change: B is NOT staged in LDS. B fragments load direct global->VGPR
// (coalesced 16B/lane, 3MB matrix is L2-resident), prefetched one iter
// ahead into ping-pong register sets bA/bB (statically indexed, rule #20).
// LDS traffic/iter halves (48KB -> 24KB, A only), LDS footprint 32->16KB,
// staging queue 4 -> 2 loads/thread/iter. tap=125: A comes from the zero
// page, so B's k-offset is simply clamped (product is 0 regardless).
// LDS XOR-swizzle (T2, both-sides) on A carried over: conflicts = 0.
// Writes offbT[v][n] f16 (+bias).
// ---------------------------------------------------------------------------
__global__ __launch_bounds__(256) void gemm_off_kernel(
    const unsigned short* __restrict__ xt,
    const unsigned short* __restrict__ Bprep,
    const float* __restrict__ b_off,
    const float* __restrict__ zpage,
    unsigned short* __restrict__ offbT)
{
    __shared__ unsigned short A_lds[2][2][64 * 32];   // [buf][h][row*32+k] 16KB

    const int t    = threadIdx.x;
    const int lane = t & 63;
    const int wave = t >> 6;
    const int wr   = wave >> 1;
    const int wc   = wave & 1;
    const int quad = lane >> 4;
    const int lrow = lane & 15;
    const int M0   = blockIdx.x * 64;
    const int N0   = blockIdx.y * 64;

    // Staging: thread t's phys LDS dest is t*16 B (linear, hardware-imposed).
    // Inverse-swizzled logical chunk it must fetch: (t&3) ^ ((t>>3)&3).
    const int srow = t >> 2;
    const int soff = ((t & 3) ^ ((t >> 3) & 3)) * 8;   // shorts, swizzled
    const int mg = M0 + srow;
    const int az = mg / 400, arm = mg % 400;
    const int ay = arm / 20, ax = arm % 20;
    const unsigned short* zp   = (const unsigned short*)zpage;
    const int ldsoff = wave * 512;          // shorts: wave's 1024B chunk
    // Read-side swizzle constant (mi/ni/wr/wc add multiples of 8 to row>>1).
    const int xorc = (lrow >> 1) & 3;

    // Per-lane B fragment base pointers (rows n = N0 + wc*32 + ni*16 + lrow;
    // n < 384 always, rows >= 375 are zeros in Bprep).
    const unsigned short* bp0 =
        Bprep + (size_t)(N0 + wc * 32 + 0 * 16 + lrow) * KK_ + quad * 8;
    const unsigned short* bp1 =
        Bprep + (size_t)(N0 + wc * 32 + 1 * 16 + lrow) * KK_ + quad * 8;

    f32x4 acc[2][2] = {};

    auto stageA = [&](int buf, int tap0) {
        #pragma unroll
        for (int h = 0; h < 2; ++h) {
            int tap = tap0 + h;
            int kz = tap / 25, ky = (tap / 5) % 5, kx = tap % 5;
            int zi = az - 2 + kz, yi = ay - 2 + ky, xi = ax - 2 + kx;
            bool ok = (tap < K3_) & ((unsigned)zi < (unsigned)S_)
                                  & ((unsigned)yi < (unsigned)S_)
                                  & ((unsigned)xi < (unsigned)S_);
            int px = zi * 400 + yi * 20 + xi;
            const unsigned short* ga = ok ? (xt + px * 32 + soff) : zp;
            __builtin_amdgcn_global_load_lds(
                (const __attribute__((address_space(1))) void*)ga,
                (__attribute__((address_space(3))) void*)(&A_lds[buf][h][ldsoff]),
                16, 0, 0);
        }
    };

    auto loadB = [&](int tap0, bf16x8 (&breg)[2][2]) {
        #pragma unroll
        for (int h = 0; h < 2; ++h) {
            int ko = min(tap0 + h, K3_ - 1) * 32;   // tap 125: A=0, B clamped
            breg[h][0] = *(const bf16x8*)(bp0 + ko);
            breg[h][1] = *(const bf16x8*)(bp1 + ko);
        }
    };

    auto compute = [&](int buf, bf16x8 (&breg)[2][2]) {
        #pragma unroll
        for (int h = 0; h < 2; ++h) {
            bf16x8 af[2];
            #pragma unroll
            for (int mi = 0; mi < 2; ++mi)
                af[mi] = *(const bf16x8*)&A_lds[buf][h]
                    [(wr * 32 + mi * 16 + lrow) * 32 + (quad ^ xorc) * 8];
            #pragma unroll
            for (int mi = 0; mi < 2; ++mi)
                #pragma unroll
                for (int ni = 0; ni < 2; ++ni)
                    acc[mi][ni] = __builtin_amdgcn_mfma_f32_16x16x32_f16(
                        af[mi], breg[h][ni], acc[mi][ni], 0, 0, 0);
        }
    };

    bf16x8 bA[2][2], bB[2][2];

    // Prologue: stage tile 0, load B tile 0.
    stageA(0, 0);
    loadB(0, bA);
    __syncthreads();

    int cur = 0;
    // 63 K-tiles, 2 per trip; ping-pong bA/bB is statically indexed.
    for (int it2 = 0; it2 < 63; it2 += 2) {
        if (it2 + 1 < 63) { stageA(cur ^ 1, (it2 + 1) * 2); loadB((it2 + 1) * 2, bB); }
        compute(cur, bA);
        __syncthreads();
        cur ^= 1;
        if (it2 + 1 < 63) {
            if (it2 + 2 < 63) { stageA(cur ^ 1, (it2 + 2) * 2); loadB((it2 + 2) * 2, bA); }
            compute(cur, bB);
            __syncthreads();
            cur ^= 1;
        }
    }

    #pragma unroll
    for (int mi = 0; mi < 2; ++mi) {
        #pragma unroll
        for (int ni = 0; ni < 2; ++ni) {
            int n = N0 + wc * 32 + ni * 16 + lrow;
            if (n < OC_) {
                float bias = b_off[n];
                #pragma unroll
                for (int r = 0; r < 4; ++r) {
                    int row = wr * 32 + mi * 16 + quad * 4 + r;
                    offbT[(size_t)(M0 + row) * 384 + n] = f2h(acc[mi][ni][r] + bias);
                }
            }
        }
    }
}

// ---------------------------------------------------------------------------
// xp[v][c] = half2(x[v][c], x[v+1][c]) — makes the (w0,w1) trilinear x-pair
// a single dword load in deform. xp[7999].y = 0 (never used with nonzero wt).
// ---------------------------------------------------------------------------
__global__ __launch_bounds__(256) void pack_xp_kernel(
    const unsigned short* __restrict__ xt, unsigned* __restrict__ xp)
{
    int i = blockIdx.x * 256 + threadIdx.x;
    if (i >= 256000) return;
    unsigned lo = xt[i];
    unsigned hi = (i < 256000 - 32) ? (unsigned)xt[i + 32] : 0u;
    xp[i] = lo | (hi << 16);
}

// ---------------------------------------------------------------------------
// Deformable depthwise sample, two-phase.
// Phase 1: per (voxel, tap) geometry -> 4 packed half2 weights (trilinear
//          factors pre-multiplied) + 4 final gather indices. 32B/entry.
// Phase 2: thread=(v,c); 2 broadcast LDS reads, 4 dword gathers, 4 fdot2.
// ---------------------------------------------------------------------------
#define VB 8
__global__ __launch_bounds__(256) void deform_kernel(
    const unsigned* __restrict__ xp,
    const float* __restrict__ wdwT,
    const float* __restrict__ b_dw,
    const unsigned short* __restrict__ offbT,
    float* __restrict__ attn1T)
{
    __shared__ unsigned sw[VB * 128 * 8];   // 32 KB, 32B per (v,tap) entry
    const int tid = threadIdx.x;
    const int Vb = blockIdx.x * VB;

    for (int idx = tid; idx < VB * 128; idx += 256) {
        int vl = idx >> 7, tap = idx & 127;
        if (tap < K3_) {
            int v = Vb + vl;
            int z = v / 400, rm = v % 400;
            int y = rm / 20, xx = rm % 20;
            int kz = tap / 25, ky = (tap / 5) % 5, kx = tap % 5;
            const unsigned short* ob = offbT + v * 384 + 3 * tap;
            float pd = (float)(z - 2 + kz) + h2f(ob[0]);
            float ph = (float)(y - 2 + ky) + h2f(ob[1]);
            float pw = (float)(xx - 2 + kx) + h2f(ob[2]);
            float fd0 = floorf(pd), fh0 = floorf(ph), fw0 = floorf(pw);
            float fd = pd - fd0, fh = ph - fh0, fw = pw - fw0;
            int id = (int)fd0, ih = (int)fh0, iw = (int)fw0;
            int d0 = min(max(id, 0), S_ - 1), d1 = min(max(id + 1, 0), S_ - 1);
            int h0 = min(max(ih, 0), S_ - 1), h1 = min(max(ih + 1, 0), S_ - 1);
            float wd0 = ((unsigned)id       < (unsigned)S_) ? 1.f - fd : 0.f;
            float wd1 = ((unsigned)(id + 1) < (unsigned)S_) ? fd       : 0.f;
            float wh0 = ((unsigned)ih       < (unsigned)S_) ? 1.f - fh : 0.f;
            float wh1 = ((unsigned)(ih + 1) < (unsigned)S_) ? fh       : 0.f;
            float ww0 = ((unsigned)iw       < (unsigned)S_) ? 1.f - fw : 0.f;
            float ww1 = ((unsigned)(iw + 1) < (unsigned)S_) ? fw       : 0.f;
            // x-pair via xp[p] = (x[p], x[p+1]); iw<0 handled by weight swap.
            int px; float wwa, wwb;
            if (iw < 0) { px = 0;             wwa = ww1; wwb = 0.f; }
            else        { px = min(iw, S_-1); wwa = ww0; wwb = ww1; }
            int r00 = d0 * 400 + h0 * 20 + px;
            int r01 = d0 * 400 + h1 * 20 + px;
            int r10 = d1 * 400 + h0 * 20 + px;
            int r11 = d1 * 400 + h1 * 20 + px;
            float w00 = wd0 * wh0, w01 = wd0 * wh1;
            float w10 = wd1 * wh0, w11 = wd1 * wh1;
            unsigned* q = &sw[idx * 8];
            q[0] = pkh2(w00 * wwa, w00 * wwb);
            q[1] = pkh2(w01 * wwa, w01 * wwb);
            q[2] = pkh2(w10 * wwa, w10 * wwb);
            q[3] = pkh2(w11 * wwa, w11 * wwb);
            q[4] = (unsigned)r00 | ((unsigned)r01 << 16);
            q[5] = (unsigned)r10 | ((unsigned)r11 << 16);
        }
    }
    __syncthreads();

    const int c = tid & 31;
    const int vl = tid >> 5;
    const int v = Vb + vl;
    const unsigned* xpc = xp + c;
    float acc = 0.f;
    #pragma unroll 4
    for (int tap = 0; tap < K3_; ++tap) {
        const unsigned* q = &sw[(vl * 128 + tap) * 8];
        unsigned w00u = q[0], w01u = q[1], w10u = q[2], w11u = q[3];
        unsigned pA = q[4], pB = q[5];
        int p00 = pA & 0xFFFFu, p01 = pA >> 16;
        int p10 = pB & 0xFFFFu, p11 = pB >> 16;
        float s = dot2(xpc[p00 * 32], w00u,
                  dot2(xpc[p01 * 32], w01u,
                  dot2(xpc[p10 * 32], w10u,
                  dot2(xpc[p11 * 32], w11u, 0.f))));
        acc += wdwT[tap * 32 + c] * s;
    }
    attn1T[v * 32 + c] = acc + b_dw[c];
}

// ---------------------------------------------------------------------------
// Depthwise 7^3 conv, dilation 3, pad 9, channel-last, coalesced.
// ---------------------------------------------------------------------------
__global__ __launch_bounds__(256) void spatial_kernel(
    const float* __restrict__ wspT,
    const float* __restrict__ b_sp,
    const float* __restrict__ attn1T,
    float* __restrict__ attn2T)
{
    int t = threadIdx.x;
    int c = t & 31;
    int v = blockIdx.x * 8 + (t >> 5);
    int z = v / 400, rm = v % 400;
    int y = rm / 20, xx = rm % 20;

    float acc = 0.f;
    #pragma unroll 1
    for (int kz = 0; kz < 7; ++kz) {
        int zi = z - 9 + 3 * kz;
        bool zv = (unsigned)zi < (unsigned)S_;
        int zc2 = min(max(zi, 0), S_ - 1);
        #pragma unroll 1
        for (int ky = 0; ky < 7; ++ky) {
            int yi = y - 9 + 3 * ky;
            bool yv = (unsigned)yi < (unsigned)S_;
            int yc2 = min(max(yi, 0), S_ - 1);
            int abase = (zc2 * 400 + yc2 * 20) * 32 + c;
            int wbase = (kz * 49 + ky * 7) * 32 + c;
            #pragma unroll
            for (int kx = 0; kx < 7; ++kx) {
                int xi = xx - 9 + 3 * kx;
                bool xv = (unsigned)xi < (unsigned)S_;
                int xc2 = min(max(xi, 0), S_ - 1);
                float a = attn1T[abase + xc2 * 32];
                float w = wspT[wbase + kx * 32];
                acc += (zv && yv && xv) ? a * w : 0.f;
            }
        }
    }
    attn2T[v * 32 + c] = acc + b_sp[c];
}

// ---------------------------------------------------------------------------
// Pointwise 32x32 + bias, gate: out[o][v] = x[o][v] * attn.
// ---------------------------------------------------------------------------
__global__ __launch_bounds__(256) void pw_kernel(
    const float* __restrict__ x,
    const float* __restrict__ wpwT,
    const float* __restrict__ b_pw,
    const float* __restrict__ attn2T,
    float* __restrict__ out)
{
    int t = threadIdx.x;
    int o = t & 31;
    int v = blockIdx.x * 8 + (t >> 5);
    float acc = b_pw[o];
    #pragma unroll
    for (int c = 0; c < C_; ++c)
        acc += wpwT[c * 32 + o] * attn2T[v * 32 + c];
    out[o * V_ + v] = x[o * V_ + v] * acc;
}

// ---------------------------------------------------------------------------
extern "C" void kernel_launch(void* const* d_in, const int* in_sizes, int n_in,
                              void* d_out, int out_size, void* d_ws, size_t ws_size,
                              hipStream_t stream)
{
    const float* x     = (const float*)d_in[0];
    const float* w_off = (const float*)d_in[1];
    const float* b_off = (const float*)d_in[2];
    const float* w_dw  = (const float*)d_in[3];
    const float* b_dw  = (const float*)d_in[4];
    const float* w_sp  = (const float*)d_in[5];
    const float* b_sp  = (const float*)d_in[6];
    const float* w_pw  = (const float*)d_in[7];
    const float* b_pw  = (const float*)d_in[8];
    float* ws = (float*)d_ws;
    float* out = (float*)d_out;

    unsigned short* xt    = (unsigned short*)(ws + WS_XT);
    unsigned short* offbT = (unsigned short*)(ws + WS_OFFB);
    unsigned short* Bprep = (unsigned short*)(ws + WS_BPREP);
    unsigned*       xp    = (unsigned*)(ws + WS_XP);

    hipLaunchKernelGGL(transpose_kernel, dim3((272016 + 255) / 256), dim3(256), 0, stream,
                       x, w_dw, w_sp, w_pw, xt,
                       ws + WS_WDWT, ws + WS_WSPT, ws + WS_WPWT, ws + WS_ZERO);

    hipLaunchKernelGGL(prep_b_kernel, dim3((NP_ * KK_ + 255) / 256), dim3(256), 0, stream,
                       w_off, Bprep);

    hipLaunchKernelGGL(gemm_off_kernel, dim3(125, 6), dim3(256), 0, stream,
                       xt, Bprep, b_off, ws + WS_ZERO, offbT);

    hipLaunchKernelGGL(pack_xp_kernel, dim3(1000), dim3(256), 0, stream,
                       xt, xp);

    hipLaunchKernelGGL(deform_kernel, dim3(1000), dim3(256), 0, stream,
                       xp, ws + WS_WDWT, b_dw, offbT, ws + WS_ATTN1T);

    hipLaunchKernelGGL(spatial_kernel, dim3(1000), dim3(256), 0, stream,
                       ws + WS_WSPT, b_sp, ws + WS_ATTN1T, ws + WS_ATTN2T);

    hipLaunchKernelGGL(pw_kernel, dim3(1000), dim3(256), 0, stream,
                       x, ws + WS_WPWT, b_pw, ws + WS_ATTN2T, out);
}

// Round 8
// 206.337 us; speedup vs baseline: 1.0963x; 1.0963x over previous
//
#include <hip/hip_runtime.h>
#include <hip/hip_bf16.h>

// Problem constants
#define C_   32
#define S_   20
#define V_   8000     // 20^3
#define K3_  125
#define OC_  375      // 3*K3
#define NP_  384      // padded N
#define KK_  4000     // 32*125

// Workspace layout (float offsets). Peak 2.704M floats = 10.82 MB (unchanged).
#define WS_ATTN1T 0                        // fp32 [v][c]          256000
#define WS_XT     256000                   // f16  [v][c]          128000 fl
#define WS_WDWT   384000                   // fp32 [k][c]            4000
#define WS_WSPT   388000                   // fp32 [k][c]           10976
#define WS_WPWT   398976                   // fp32 [c][o]            1024
#define WS_OFFB   400000                   // f16  [v][384]       1536000 fl
#define WS_BPREP  1936000                  // f16 [n][k] 768000 fl; dead after gemm
#define WS_XP     1936000                  //   -> reused: half2 [v][c] 256000 fl
#define WS_ATTN2T 2192000                  //   -> reused: fp32 [v][c] 256000 fl
// Zero page: first 16 floats of ATTN1T region (dead until deform_kernel).
#define WS_ZERO   WS_ATTN1T

typedef __attribute__((ext_vector_type(8))) short bf16x8;
typedef __attribute__((ext_vector_type(4))) float f32x4;
typedef __fp16 h2_t __attribute__((ext_vector_type(2)));   // matches builtins

static __device__ __forceinline__ unsigned short f2h(float f) {
    _Float16 h = (_Float16)f;
    return __builtin_bit_cast(unsigned short, h);
}
static __device__ __forceinline__ float h2f(unsigned short b) {
    return (float)__builtin_bit_cast(_Float16, b);
}
static __device__ __forceinline__ h2_t bch2(unsigned u) {
    return __builtin_bit_cast(h2_t, u);
}
static __device__ __forceinline__ unsigned pkh2(float a, float b) {
#if __has_builtin(__builtin_amdgcn_cvt_pkrtz)
    return __builtin_bit_cast(unsigned, __builtin_amdgcn_cvt_pkrtz(a, b));
#else
    return (unsigned)f2h(a) | ((unsigned)f2h(b) << 16);
#endif
}
static __device__ __forceinline__ float dot2(unsigned xu, unsigned wu, float c) {
#if __has_builtin(__builtin_amdgcn_fdot2)
    return __builtin_amdgcn_fdot2(bch2(xu), bch2(wu), c, false);
#else
    h2_t xh = bch2(xu), wh = bch2(wu);
    return c + (float)xh[0] * (float)wh[0] + (float)xh[1] * (float)wh[1];
#endif
}

// ---------------------------------------------------------------------------
// Transposes: xt[v][c] f16; wdwT[k][c]; wspT[k][c]; wpwT[c][o] (fp32).
// Also zeroes the 64B zero page used by gemm's OOB lane redirect.
// ---------------------------------------------------------------------------
__global__ __launch_bounds__(256) void transpose_kernel(
    const float* __restrict__ x,
    const float* __restrict__ w_dw,
    const float* __restrict__ w_sp,
    const float* __restrict__ w_pw,
    unsigned short* __restrict__ xt,
    float* __restrict__ wdwT,
    float* __restrict__ wspT,
    float* __restrict__ wpwT,
    float* __restrict__ zpage)
{
    int i = blockIdx.x * 256 + threadIdx.x;
    if (i < 256000) {
        int v = i >> 5, c = i & 31;
        xt[i] = f2h(x[c * V_ + v]);
        return;
    }
    int j = i - 256000;
    if (j < 4000)  { wdwT[j] = w_dw[(j & 31) * K3_ + (j >> 5)]; return; }
    j -= 4000;
    if (j < 10976) { wspT[j] = w_sp[(j & 31) * 343 + (j >> 5)]; return; }
    j -= 10976;
    if (j < 1024)  { wpwT[j] = w_pw[(j & 31) * 32 + (j >> 5)]; return; }
    j -= 1024;
    if (j < 16)    { zpage[j] = 0.f; return; }
}

// ---------------------------------------------------------------------------
// Weight transform: Bprep[n][k] f16, k = tap*32 + c; n >= 375 zeroed.
// ---------------------------------------------------------------------------
__global__ __launch_bounds__(256) void prep_b_kernel(
    const float* __restrict__ w_off, unsigned short* __restrict__ Bprep)
{
    int idx = blockIdx.x * 256 + threadIdx.x;
    if (idx >= NP_ * KK_) return;
    int n = idx / KK_, r = idx % KK_;
    int tap = r >> 5, c = r & 31;
    float v = (n < OC_) ? w_off[n * KK_ + c * K3_ + tap] : 0.f;
    Bprep[idx] = f2h(v);
}

// ---------------------------------------------------------------------------
// Offset conv as implicit-GEMM MFMA (f16): D[8000][384] = A[8000][4000]*B.
// CUBE SCHEME: M-tile = 4x4x4 voxel cube. The entire A K-panel for this
// tile is reads of the 8x8x8 halo cube of xt (32 KB) -> staged into LDS
// ONCE (8 global_load_lds/thread, OOB -> zero page), one barrier, then the
// K-loop has NO barriers. Per tap, A fragment = ds_read_b128 from the cube
// at a wave-uniform tap offset (bank-uniform: 8 words/bank, no swizzle
// needed). B loads direct global->VGPR with 1-iter ping-pong prefetch
// (bA/bB statically indexed) — works now because no barrier drains vmcnt.
// Taps: main loop 62 iters x 2 taps (0..123) + epilogue tap 124 (one
// K=32 MFMA) — no padding tap in the hot loop.
// Row mapping: block row br -> voxel (vz,vy,vx) = (br>>4,(br>>2)&3,br&3);
// A-read side br = wr*32+mi*16+lrow, C-side br = wr*32+mi*16+quad*4+r.
// Writes offbT[v][n] f16 (+bias), v = exact voxel id.
// ---------------------------------------------------------------------------
__global__ __launch_bounds__(256) void gemm_off_kernel(
    const unsigned short* __restrict__ xt,
    const unsigned short* __restrict__ Bprep,
    const float* __restrict__ b_off,
    const float* __restrict__ zpage,
    unsigned short* __restrict__ offbT)
{
    __shared__ unsigned short cube[512 * 32];   // 8x8x8 voxels x 32ch = 32 KB

    const int t    = threadIdx.x;
    const int lane = t & 63;
    const int wave = t >> 6;
    const int wr   = wave >> 1;
    const int wc   = wave & 1;
    const int quad = lane >> 4;
    const int lrow = lane & 15;

    const int bx = blockIdx.x;                  // 0..124 cube index
    const int Z0 = (bx / 25) * 4;
    const int Y0 = ((bx / 5) % 5) * 4;
    const int X0 = (bx % 5) * 4;
    const int N0 = blockIdx.y * 64;

    const unsigned short* zp = (const unsigned short*)zpage;

    // ---- Stage halo cube once: 512 rows x 64B = 2048 x 16B chunks. ----
    #pragma unroll
    for (int g = 0; g < 8; ++g) {
        int ch  = t + 256 * g;
        int row = ch >> 2;                      // voxel index in cube
        int hz = row >> 6, hy = (row >> 3) & 7, hx = row & 7;
        int z = Z0 - 2 + hz, y = Y0 - 2 + hy, x = X0 - 2 + hx;
        bool ok = ((unsigned)z < (unsigned)S_) & ((unsigned)y < (unsigned)S_)
                                               & ((unsigned)x < (unsigned)S_);
        const unsigned short* src =
            ok ? (xt + (z * 400 + y * 20 + x) * 32 + (ch & 3) * 8) : zp;
        __builtin_amdgcn_global_load_lds(
            (const __attribute__((address_space(1))) void*)src,
            (__attribute__((address_space(3))) void*)(&cube[ch * 8]),
            16, 0, 0);
    }
    __syncthreads();    // the ONLY barrier

    // Per-lane B fragment base pointers (rows n = N0 + wc*32 + ni*16 + lrow;
    // n < 384 always, rows >= 375 are zeros in Bprep).
    const unsigned short* bp0 =
        Bprep + (size_t)(N0 + wc * 32 + 0 * 16 + lrow) * KK_ + quad * 8;
    const unsigned short* bp1 =
        Bprep + (size_t)(N0 + wc * 32 + 1 * 16 + lrow) * KK_ + quad * 8;

    const int vy = lrow >> 2, vx = lrow & 3;

    f32x4 acc[2][2] = {};

    auto loadB = [&](int tap0, bf16x8 (&breg)[2][2]) {
        #pragma unroll
        for (int h = 0; h < 2; ++h) {
            int ko = (tap0 + h) * 32;
            breg[h][0] = *(const bf16x8*)(bp0 + ko);
            breg[h][1] = *(const bf16x8*)(bp1 + ko);
        }
    };

    auto computeT = [&](int tap, const bf16x8 (&bh)[2]) {
        int kz = tap / 25, ky = (tap / 5) % 5, kx = tap % 5;
        int pbase = (vy + ky) * 8 + (vx + kx);  // plane part, per-lane
        bf16x8 af[2];
        #pragma unroll
        for (int mi = 0; mi < 2; ++mi) {
            int voxel = ((wr * 2 + mi + kz) << 6) + pbase;
            af[mi] = *(const bf16x8*)&cube[voxel * 32 + quad * 8];
        }
        #pragma unroll
        for (int mi = 0; mi < 2; ++mi)
            #pragma unroll
            for (int ni = 0; ni < 2; ++ni)
                acc[mi][ni] = __builtin_amdgcn_mfma_f32_16x16x32_f16(
                    af[mi], bh[ni], acc[mi][ni], 0, 0, 0);
    };

    bf16x8 bA[2][2], bB[2][2];
    loadB(0, bA);                               // taps 0,1

    // 62 iters x 2 taps (0..123), manually unrolled x2, 1-iter B prefetch.
    #pragma unroll 1
    for (int it2 = 0; it2 < 62; it2 += 2) {
        loadB((it2 + 1) * 2, bB);               // prefetch iter it2+1
        computeT(it2 * 2,     bA[0]);
        computeT(it2 * 2 + 1, bA[1]);
        if (it2 + 2 < 62) loadB((it2 + 2) * 2, bA);
        computeT((it2 + 1) * 2,     bB[0]);
        computeT((it2 + 1) * 2 + 1, bB[1]);
    }

    // Epilogue: tap 124 (single K=32 MFMA per fragment).
    {
        bf16x8 bE[2];
        bE[0] = *(const bf16x8*)(bp0 + 124 * 32);
        bE[1] = *(const bf16x8*)(bp1 + 124 * 32);
        computeT(124, bE);
    }

    #pragma unroll
    for (int mi = 0; mi < 2; ++mi) {
        #pragma unroll
        for (int ni = 0; ni < 2; ++ni) {
            int n = N0 + wc * 32 + ni * 16 + lrow;
            if (n < OC_) {
                float bias = b_off[n];
                int z = Z0 + wr * 2 + mi;
                #pragma unroll
                for (int r = 0; r < 4; ++r) {
                    int v = z * 400 + (Y0 + quad) * 20 + (X0 + r);
                    offbT[(size_t)v * 384 + n] = f2h(acc[mi][ni][r] + bias);
                }
            }
        }
    }
}

// ---------------------------------------------------------------------------
// xp[v][c] = half2(x[v][c], x[v+1][c]) — makes the (w0,w1) trilinear x-pair
// a single dword load in deform. xp[7999].y = 0 (never used with nonzero wt).
// ---------------------------------------------------------------------------
__global__ __launch_bounds__(256) void pack_xp_kernel(
    const unsigned short* __restrict__ xt, unsigned* __restrict__ xp)
{
    int i = blockIdx.x * 256 + threadIdx.x;
    if (i >= 256000) return;
    unsigned lo = xt[i];
    unsigned hi = (i < 256000 - 32) ? (unsigned)xt[i + 32] : 0u;
    xp[i] = lo | (hi << 16);
}

// ---------------------------------------------------------------------------
// Deformable depthwise sample, two-phase.
// Phase 1: per (voxel, tap) geometry -> 4 packed half2 weights (trilinear
//          factors pre-multiplied) + 4 final gather indices. 32B/entry.
// Phase 2: thread=(v,c); 2 broadcast LDS reads, 4 dword gathers, 4 fdot2.
// ---------------------------------------------------------------------------
#define VB 8
__global__ __launch_bounds__(256) void deform_kernel(
    const unsigned* __restrict__ xp,
    const float* __restrict__ wdwT,
    const float* __restrict__ b_dw,
    const unsigned short* __restrict__ offbT,
    float* __restrict__ attn1T)
{
    __shared__ unsigned sw[VB * 128 * 8];   // 32 KB, 32B per (v,tap) entry
    const int tid = threadIdx.x;
    const int Vb = blockIdx.x * VB;

    for (int idx = tid; idx < VB * 128; idx += 256) {
        int vl = idx >> 7, tap = idx & 127;
        if (tap < K3_) {
            int v = Vb + vl;
            int z = v / 400, rm = v % 400;
            int y = rm / 20, xx = rm % 20;
            int kz = tap / 25, ky = (tap / 5) % 5, kx = tap % 5;
            const unsigned short* ob = offbT + v * 384 + 3 * tap;
            float pd = (float)(z - 2 + kz) + h2f(ob[0]);
            float ph = (float)(y - 2 + ky) + h2f(ob[1]);
            float pw = (float)(xx - 2 + kx) + h2f(ob[2]);
            float fd0 = floorf(pd), fh0 = floorf(ph), fw0 = floorf(pw);
            float fd = pd - fd0, fh = ph - fh0, fw = pw - fw0;
            int id = (int)fd0, ih = (int)fh0, iw = (int)fw0;
            int d0 = min(max(id, 0), S_ - 1), d1 = min(max(id + 1, 0), S_ - 1);
            int h0 = min(max(ih, 0), S_ - 1), h1 = min(max(ih + 1, 0), S_ - 1);
            float wd0 = ((unsigned)id       < (unsigned)S_) ? 1.f - fd : 0.f;
            float wd1 = ((unsigned)(id + 1) < (unsigned)S_) ? fd       : 0.f;
            float wh0 = ((unsigned)ih       < (unsigned)S_) ? 1.f - fh : 0.f;
            float wh1 = ((unsigned)(ih + 1) < (unsigned)S_) ? fh       : 0.f;
            float ww0 = ((unsigned)iw       < (unsigned)S_) ? 1.f - fw : 0.f;
            float ww1 = ((unsigned)(iw + 1) < (unsigned)S_) ? fw       : 0.f;
            // x-pair via xp[p] = (x[p], x[p+1]); iw<0 handled by weight swap.
            int px; float wwa, wwb;
            if (iw < 0) { px = 0;             wwa = ww1; wwb = 0.f; }
            else        { px = min(iw, S_-1); wwa = ww0; wwb = ww1; }
            int r00 = d0 * 400 + h0 * 20 + px;
            int r01 = d0 * 400 + h1 * 20 + px;
            int r10 = d1 * 400 + h0 * 20 + px;
            int r11 = d1 * 400 + h1 * 20 + px;
            float w00 = wd0 * wh0, w01 = wd0 * wh1;
            float w10 = wd1 * wh0, w11 = wd1 * wh1;
            unsigned* q = &sw[idx * 8];
            q[0] = pkh2(w00 * wwa, w00 * wwb);
            q[1] = pkh2(w01 * wwa, w01 * wwb);
            q[2] = pkh2(w10 * wwa, w10 * wwb);
            q[3] = pkh2(w11 * wwa, w11 * wwb);
            q[4] = (unsigned)r00 | ((unsigned)r01 << 16);
            q[5] = (unsigned)r10 | ((unsigned)r11 << 16);
        }
    }
    __syncthreads();

    const int c = tid & 31;
    const int vl = tid >> 5;
    const int v = Vb + vl;
    const unsigned* xpc = xp + c;
    float acc = 0.f;
    #pragma unroll 4
    for (int tap = 0; tap < K3_; ++tap) {
        const unsigned* q = &sw[(vl * 128 + tap) * 8];
        unsigned w00u = q[0], w01u = q[1], w10u = q[2], w11u = q[3];
        unsigned pA = q[4], pB = q[5];
        int p00 = pA & 0xFFFFu, p01 = pA >> 16;
        int p10 = pB & 0xFFFFu, p11 = pB >> 16;
        float s = dot2(xpc[p00 * 32], w00u,
                  dot2(xpc[p01 * 32], w01u,
                  dot2(xpc[p10 * 32], w10u,
                  dot2(xpc[p11 * 32], w11u, 0.f))));
        acc += wdwT[tap * 32 + c] * s;
    }
    attn1T[v * 32 + c] = acc + b_dw[c];
}

// ---------------------------------------------------------------------------
// Depthwise 7^3 conv, dilation 3, pad 9, channel-last, coalesced.
// ---------------------------------------------------------------------------
__global__ __launch_bounds__(256) void spatial_kernel(
    const float* __restrict__ wspT,
    const float* __restrict__ b_sp,
    const float* __restrict__ attn1T,
    float* __restrict__ attn2T)
{
    int t = threadIdx.x;
    int c = t & 31;
    int v = blockIdx.x * 8 + (t >> 5);
    int z = v / 400, rm = v % 400;
    int y = rm / 20, xx = rm % 20;

    float acc = 0.f;
    #pragma unroll 1
    for (int kz = 0; kz < 7; ++kz) {
        int zi = z - 9 + 3 * kz;
        bool zv = (unsigned)zi < (unsigned)S_;
        int zc2 = min(max(zi, 0), S_ - 1);
        #pragma unroll 1
        for (int ky = 0; ky < 7; ++ky) {
            int yi = y - 9 + 3 * ky;
            bool yv = (unsigned)yi < (unsigned)S_;
            int yc2 = min(max(yi, 0), S_ - 1);
            int abase = (zc2 * 400 + yc2 * 20) * 32 + c;
            int wbase = (kz * 49 + ky * 7) * 32 + c;
            #pragma unroll
            for (int kx = 0; kx < 7; ++kx) {
                int xi = xx - 9 + 3 * kx;
                bool xv = (unsigned)xi < (unsigned)S_;
                int xc2 = min(max(xi, 0), S_ - 1);
                float a = attn1T[abase + xc2 * 32];
                float w = wspT[wbase + kx * 32];
                acc += (zv && yv && xv) ? a * w : 0.f;
            }
        }
    }
    attn2T[v * 32 + c] = acc + b_sp[c];
}

// ---------------------------------------------------------------------------
// Pointwise 32x32 + bias, gate: out[o][v] = x[o][v] * attn.
// ---------------------------------------------------------------------------
__global__ __launch_bounds__(256) void pw_kernel(
    const float* __restrict__ x,
    const float* __restrict__ wpwT,
    const float* __restrict__ b_pw,
    const float* __restrict__ attn2T,
    float* __restrict__ out)
{
    int t = threadIdx.x;
    int o = t & 31;
    int v = blockIdx.x * 8 + (t >> 5);
    float acc = b_pw[o];
    #pragma unroll
    for (int c = 0; c < C_; ++c)
        acc += wpwT[c * 32 + o] * attn2T[v * 32 + c];
    out[o * V_ + v] = x[o * V_ + v] * acc;
}

// ---------------------------------------------------------------------------
extern "C" void kernel_launch(void* const* d_in, const int* in_sizes, int n_in,
                              void* d_out, int out_size, void* d_ws, size_t ws_size,
                              hipStream_t stream)
{
    const float* x     = (const float*)d_in[0];
    const float* w_off = (const float*)d_in[1];
    const float* b_off = (const float*)d_in[2];
    const float* w_dw  = (const float*)d_in[3];
    const float* b_dw  = (const float*)d_in[4];
    const float* w_sp  = (const float*)d_in[5];
    const float* b_sp  = (const float*)d_in[6];
    const float* w_pw  = (const float*)d_in[7];
    const float* b_pw  = (const float*)d_in[8];
    float* ws = (float*)d_ws;
    float* out = (float*)d_out;

    unsigned short* xt    = (unsigned short*)(ws + WS_XT);
    unsigned short* offbT = (unsigned short*)(ws + WS_OFFB);
    unsigned short* Bprep = (unsigned short*)(ws + WS_BPREP);
    unsigned*       xp    = (unsigned*)(ws + WS_XP);

    hipLaunchKernelGGL(transpose_kernel, dim3((272016 + 255) / 256), dim3(256), 0, stream,
                       x, w_dw, w_sp, w_pw, xt,
                       ws + WS_WDWT, ws + WS_WSPT, ws + WS_WPWT, ws + WS_ZERO);

    hipLaunchKernelGGL(prep_b_kernel, dim3((NP_ * KK_ + 255) / 256), dim3(256), 0, stream,
                       w_off, Bprep);

    hipLaunchKernelGGL(gemm_off_kernel, dim3(125, 6), dim3(256), 0, stream,
                       xt, Bprep, b_off, ws + WS_ZERO, offbT);

    hipLaunchKernelGGL(pack_xp_kernel, dim3(1000), dim3(256), 0, stream,
                       xt, xp);

    hipLaunchKernelGGL(deform_kernel, dim3(1000), dim3(256), 0, stream,
                       xp, ws + WS_WDWT, b_dw, offbT, ws + WS_ATTN1T);

    hipLaunchKernelGGL(spatial_kernel, dim3(1000), dim3(256), 0, stream,
                       ws + WS_WSPT, b_sp, ws + WS_ATTN1T, ws + WS_ATTN2T);

    hipLaunchKernelGGL(pw_kernel, dim3(1000), dim3(256), 0, stream,
                       x, ws + WS_WPWT, b_pw, ws + WS_ATTN2T, out);
}

// Round 9
// 191.107 us; speedup vs baseline: 1.1836x; 1.0797x over previous
//
#include <hip/hip_runtime.h>
#include <hip/hip_bf16.h>

// Problem constants
#define C_   32
#define S_   20
#define V_   8000     // 20^3
#define K3_  125
#define OC_  375      // 3*K3
#define NP_  384      // padded N
#define KK_  4000     // 32*125

// Workspace layout (float offsets). Peak 2.704M floats = 10.82 MB (unchanged).
#define WS_ATTN1T 0                        // fp32 [v][c]          256000
#define WS_XT     256000                   // f16  [v][c]          128000 fl
#define WS_WDWT   384000                   // fp32 [k][c]            4000
#define WS_WSPT   388000                   // fp32 [k][c]           10976
#define WS_WPWT   398976                   // fp32 [c][o]            1024
#define WS_OFFB   400000                   // f16  [v][384]       1536000 fl
#define WS_BPREP  1936000                  // f16 [n][k] 768000 fl; dead after gemm
#define WS_XP     1936000                  //   -> reused: half2 [v][c] 256000 fl
// Zero page: first 16 floats of ATTN1T region (dead until deform_kernel).
#define WS_ZERO   WS_ATTN1T

typedef __attribute__((ext_vector_type(8))) short bf16x8;
typedef __attribute__((ext_vector_type(4))) float f32x4;
typedef __fp16 h2_t __attribute__((ext_vector_type(2)));   // matches builtins

static __device__ __forceinline__ unsigned short f2h(float f) {
    _Float16 h = (_Float16)f;
    return __builtin_bit_cast(unsigned short, h);
}
static __device__ __forceinline__ float h2f(unsigned short b) {
    return (float)__builtin_bit_cast(_Float16, b);
}
static __device__ __forceinline__ h2_t bch2(unsigned u) {
    return __builtin_bit_cast(h2_t, u);
}
static __device__ __forceinline__ unsigned pkh2(float a, float b) {
#if __has_builtin(__builtin_amdgcn_cvt_pkrtz)
    return __builtin_bit_cast(unsigned, __builtin_amdgcn_cvt_pkrtz(a, b));
#else
    return (unsigned)f2h(a) | ((unsigned)f2h(b) << 16);
#endif
}
static __device__ __forceinline__ float dot2(unsigned xu, unsigned wu, float c) {
#if __has_builtin(__builtin_amdgcn_fdot2)
    return __builtin_amdgcn_fdot2(bch2(xu), bch2(wu), c, false);
#else
    h2_t xh = bch2(xu), wh = bch2(wu);
    return c + (float)xh[0] * (float)wh[0] + (float)xh[1] * (float)wh[1];
#endif
}

// ---------------------------------------------------------------------------
// Transposes: xt[v][c] f16; wdwT[k][c]; wspT[k][c]; wpwT[c][o] (fp32).
// Also zeroes the 64B zero page used by gemm's OOB lane redirect.
// ---------------------------------------------------------------------------
__global__ __launch_bounds__(256) void transpose_kernel(
    const float* __restrict__ x,
    const float* __restrict__ w_dw,
    const float* __restrict__ w_sp,
    const float* __restrict__ w_pw,
    unsigned short* __restrict__ xt,
    float* __restrict__ wdwT,
    float* __restrict__ wspT,
    float* __restrict__ wpwT,
    float* __restrict__ zpage)
{
    int i = blockIdx.x * 256 + threadIdx.x;
    if (i < 256000) {
        int v = i >> 5, c = i & 31;
        xt[i] = f2h(x[c * V_ + v]);
        return;
    }
    int j = i - 256000;
    if (j < 4000)  { wdwT[j] = w_dw[(j & 31) * K3_ + (j >> 5)]; return; }
    j -= 4000;
    if (j < 10976) { wspT[j] = w_sp[(j & 31) * 343 + (j >> 5)]; return; }
    j -= 10976;
    if (j < 1024)  { wpwT[j] = w_pw[(j & 31) * 32 + (j >> 5)]; return; }
    j -= 1024;
    if (j < 16)    { zpage[j] = 0.f; return; }
}

// ---------------------------------------------------------------------------
// Weight transform: Bprep[n][k] f16, k = tap*32 + c; n >= 375 zeroed.
// ---------------------------------------------------------------------------
__global__ __launch_bounds__(256) void prep_b_kernel(
    const float* __restrict__ w_off, unsigned short* __restrict__ Bprep)
{
    int idx = blockIdx.x * 256 + threadIdx.x;
    if (idx >= NP_ * KK_) return;
    int n = idx / KK_, r = idx % KK_;
    int tap = r >> 5, c = r & 31;
    float v = (n < OC_) ? w_off[n * KK_ + c * K3_ + tap] : 0.f;
    Bprep[idx] = f2h(v);
}

// ---------------------------------------------------------------------------
// Offset conv as implicit-GEMM MFMA (f16): D[8000][384] = A[8000][4000]*B.
// EXACT R4 STRUCTURE (verified best: 53.5us, conflicts=0). Tile 64x64,
// BK=64 (2 taps/iter), 4 waves 2x2, wave tile 32x32. 2-phase pipeline,
// global_load_lds staging, double-buffered LDS (32KB), one barrier/K-step.
// LDS XOR-swizzle (T2, both-sides): write side fetches inverse-swizzled
// global chunk (linear LDS dest); read side XORs quad with (lrow>>1)&3.
// Ledger (R5-R8): 128-tile, counted-vmcnt 4-buf, B-in-VGPR, cube scheme
// all regressed (occupancy / barrier-drain / bank-uniformity). Keep R4.
// Writes offbT[v][n] f16 (+bias).
// ---------------------------------------------------------------------------
__global__ __launch_bounds__(256) void gemm_off_kernel(
    const unsigned short* __restrict__ xt,
    const unsigned short* __restrict__ Bprep,
    const float* __restrict__ b_off,
    const float* __restrict__ zpage,
    unsigned short* __restrict__ offbT)
{
    __shared__ unsigned short A_lds[2][2][64 * 32];   // [buf][h][row*32+k]
    __shared__ unsigned short B_lds[2][2][64 * 32];

    const int t    = threadIdx.x;
    const int lane = t & 63;
    const int wave = t >> 6;
    const int wr   = wave >> 1;
    const int wc   = wave & 1;
    const int quad = lane >> 4;
    const int lrow = lane & 15;
    const int M0   = blockIdx.x * 64;
    const int N0   = blockIdx.y * 64;

    const int srow = t >> 2;
    const int soff = ((t & 3) ^ ((t >> 3) & 3)) * 8;   // shorts, swizzled
    const int mg = M0 + srow;
    const int az = mg / 400, arm = mg % 400;
    const int ay = arm / 20, ax = arm % 20;
    const unsigned short* brow = Bprep + (size_t)(N0 + srow) * KK_;
    const unsigned short* zp   = (const unsigned short*)zpage;
    const int ldsoff = wave * 512;          // shorts: wave's 1024B chunk
    const int xorc = (lrow >> 1) & 3;

    f32x4 acc[2][2] = {};

    auto stage = [&](int buf, int tap0) {
        #pragma unroll
        for (int h = 0; h < 2; ++h) {
            int tap = tap0 + h;
            int kz = tap / 25, ky = (tap / 5) % 5, kx = tap % 5;
            int zi = az - 2 + kz, yi = ay - 2 + ky, xi = ax - 2 + kx;
            bool intap = tap < K3_;
            bool ok = intap & ((unsigned)zi < (unsigned)S_)
                            & ((unsigned)yi < (unsigned)S_)
                            & ((unsigned)xi < (unsigned)S_);
            int px = zi * 400 + yi * 20 + xi;
            const unsigned short* ga = ok    ? (xt + px * 32 + soff)    : zp;
            const unsigned short* gb = intap ? (brow + tap * 32 + soff) : zp;
            __builtin_amdgcn_global_load_lds(
                (const __attribute__((address_space(1))) void*)ga,
                (__attribute__((address_space(3))) void*)(&A_lds[buf][h][ldsoff]),
                16, 0, 0);
            __builtin_amdgcn_global_load_lds(
                (const __attribute__((address_space(1))) void*)gb,
                (__attribute__((address_space(3))) void*)(&B_lds[buf][h][ldsoff]),
                16, 0, 0);
        }
    };

    stage(0, 0);
    __syncthreads();

    int cur = 0;
    for (int it = 0; it < 63; ++it) {
        if (it < 62) stage(cur ^ 1, (it + 1) * 2);
        #pragma unroll
        for (int h = 0; h < 2; ++h) {
            bf16x8 af[2], bf[2];
            #pragma unroll
            for (int mi = 0; mi < 2; ++mi)
                af[mi] = *(const bf16x8*)&A_lds[cur][h][(wr * 32 + mi * 16 + lrow) * 32 + (quad ^ xorc) * 8];
            #pragma unroll
            for (int ni = 0; ni < 2; ++ni)
                bf[ni] = *(const bf16x8*)&B_lds[cur][h][(wc * 32 + ni * 16 + lrow) * 32 + (quad ^ xorc) * 8];
            #pragma unroll
            for (int mi = 0; mi < 2; ++mi)
                #pragma unroll
                for (int ni = 0; ni < 2; ++ni)
                    acc[mi][ni] = __builtin_amdgcn_mfma_f32_16x16x32_f16(
                        af[mi], bf[ni], acc[mi][ni], 0, 0, 0);
        }
        __syncthreads();
        cur ^= 1;
    }

    #pragma unroll
    for (int mi = 0; mi < 2; ++mi) {
        #pragma unroll
        for (int ni = 0; ni < 2; ++ni) {
            int n = N0 + wc * 32 + ni * 16 + lrow;
            if (n < OC_) {
                float bias = b_off[n];
                #pragma unroll
                for (int r = 0; r < 4; ++r) {
                    int row = wr * 32 + mi * 16 + quad * 4 + r;
                    offbT[(size_t)(M0 + row) * 384 + n] = f2h(acc[mi][ni][r] + bias);
                }
            }
        }
    }
}

// ---------------------------------------------------------------------------
// xp[v][c] = half2(x[v][c], x[v+1][c]) — makes the (w0,w1) trilinear x-pair
// a single dword load in deform. xp[7999].y = 0 (never used with nonzero wt).
// (Must run after gemm: xp aliases Bprep.)
// ---------------------------------------------------------------------------
__global__ __launch_bounds__(256) void pack_xp_kernel(
    const unsigned short* __restrict__ xt, unsigned* __restrict__ xp)
{
    int i = blockIdx.x * 256 + threadIdx.x;
    if (i >= 256000) return;
    unsigned lo = xt[i];
    unsigned hi = (i < 256000 - 32) ? (unsigned)xt[i + 32] : 0u;
    xp[i] = lo | (hi << 16);
}

// ---------------------------------------------------------------------------
// Deformable depthwise sample, two-phase.
// Phase 1: per (voxel, tap) geometry -> 4 packed half2 weights (trilinear
//          factors pre-multiplied) + 4 final gather indices. 32B/entry.
// Phase 2: thread=(v,c); 2 broadcast LDS reads, 4 dword gathers, 4 fdot2.
// ---------------------------------------------------------------------------
#define VB 8
__global__ __launch_bounds__(256) void deform_kernel(
    const unsigned* __restrict__ xp,
    const float* __restrict__ wdwT,
    const float* __restrict__ b_dw,
    const unsigned short* __restrict__ offbT,
    float* __restrict__ attn1T)
{
    __shared__ unsigned sw[VB * 128 * 8];   // 32 KB, 32B per (v,tap) entry
    const int tid = threadIdx.x;
    const int Vb = blockIdx.x * VB;

    for (int idx = tid; idx < VB * 128; idx += 256) {
        int vl = idx >> 7, tap = idx & 127;
        if (tap < K3_) {
            int v = Vb + vl;
            int z = v / 400, rm = v % 400;
            int y = rm / 20, xx = rm % 20;
            int kz = tap / 25, ky = (tap / 5) % 5, kx = tap % 5;
            const unsigned short* ob = offbT + v * 384 + 3 * tap;
            float pd = (float)(z - 2 + kz) + h2f(ob[0]);
            float ph = (float)(y - 2 + ky) + h2f(ob[1]);
            float pw = (float)(xx - 2 + kx) + h2f(ob[2]);
            float fd0 = floorf(pd), fh0 = floorf(ph), fw0 = floorf(pw);
            float fd = pd - fd0, fh = ph - fh0, fw = pw - fw0;
            int id = (int)fd0, ih = (int)fh0, iw = (int)fw0;
            int d0 = min(max(id, 0), S_ - 1), d1 = min(max(id + 1, 0), S_ - 1);
            int h0 = min(max(ih, 0), S_ - 1), h1 = min(max(ih + 1, 0), S_ - 1);
            float wd0 = ((unsigned)id       < (unsigned)S_) ? 1.f - fd : 0.f;
            float wd1 = ((unsigned)(id + 1) < (unsigned)S_) ? fd       : 0.f;
            float wh0 = ((unsigned)ih       < (unsigned)S_) ? 1.f - fh : 0.f;
            float wh1 = ((unsigned)(ih + 1) < (unsigned)S_) ? fh       : 0.f;
            float ww0 = ((unsigned)iw       < (unsigned)S_) ? 1.f - fw : 0.f;
            float ww1 = ((unsigned)(iw + 1) < (unsigned)S_) ? fw       : 0.f;
            // x-pair via xp[p] = (x[p], x[p+1]); iw<0 handled by weight swap.
            int px; float wwa, wwb;
            if (iw < 0) { px = 0;             wwa = ww1; wwb = 0.f; }
            else        { px = min(iw, S_-1); wwa = ww0; wwb = ww1; }
            int r00 = d0 * 400 + h0 * 20 + px;
            int r01 = d0 * 400 + h1 * 20 + px;
            int r10 = d1 * 400 + h0 * 20 + px;
            int r11 = d1 * 400 + h1 * 20 + px;
            float w00 = wd0 * wh0, w01 = wd0 * wh1;
            float w10 = wd1 * wh0, w11 = wd1 * wh1;
            unsigned* q = &sw[idx * 8];
            q[0] = pkh2(w00 * wwa, w00 * wwb);
            q[1] = pkh2(w01 * wwa, w01 * wwb);
            q[2] = pkh2(w10 * wwa, w10 * wwb);
            q[3] = pkh2(w11 * wwa, w11 * wwb);
            q[4] = (unsigned)r00 | ((unsigned)r01 << 16);
            q[5] = (unsigned)r10 | ((unsigned)r11 << 16);
        }
    }
    __syncthreads();

    const int c = tid & 31;
    const int vl = tid >> 5;
    const int v = Vb + vl;
    const unsigned* xpc = xp + c;
    float acc = 0.f;
    #pragma unroll 4
    for (int tap = 0; tap < K3_; ++tap) {
        const unsigned* q = &sw[(vl * 128 + tap) * 8];
        unsigned w00u = q[0], w01u = q[1], w10u = q[2], w11u = q[3];
        unsigned pA = q[4], pB = q[5];
        int p00 = pA & 0xFFFFu, p01 = pA >> 16;
        int p10 = pB & 0xFFFFu, p11 = pB >> 16;
        float s = dot2(xpc[p00 * 32], w00u,
                  dot2(xpc[p01 * 32], w01u,
                  dot2(xpc[p10 * 32], w10u,
                  dot2(xpc[p11 * 32], w11u, 0.f))));
        acc += wdwT[tap * 32 + c] * s;
    }
    attn1T[v * 32 + c] = acc + b_dw[c];
}

// ---------------------------------------------------------------------------
// FUSED: depthwise 7^3 conv (dil 3, pad 9) + pointwise 32x32 + gate.
// Phase A: thread (vl,c) computes spatial value -> s_attn[vl][c] (1 KB LDS).
// Phase B: thread (vl,o=c) computes out[o][v] = x[o][v] *
//          (b_pw[o] + sum_c wpwT[c][o]*s_attn[vl][c]).
// LDS reads in phase B are uniform per 32-lane c-group -> broadcast, free.
// Removes the attn2T 1MB write + 1MB read + one launch.
// ---------------------------------------------------------------------------
__global__ __launch_bounds__(256) void spatial_pw_kernel(
    const float* __restrict__ wspT,
    const float* __restrict__ b_sp,
    const float* __restrict__ attn1T,
    const float* __restrict__ wpwT,
    const float* __restrict__ b_pw,
    const float* __restrict__ x,
    float* __restrict__ out)
{
    __shared__ float s_attn[8][32];
    int t = threadIdx.x;
    int c = t & 31;
    int vl = t >> 5;
    int v = blockIdx.x * 8 + vl;
    int z = v / 400, rm = v % 400;
    int y = rm / 20, xx = rm % 20;

    float acc = 0.f;
    #pragma unroll 1
    for (int kz = 0; kz < 7; ++kz) {
        int zi = z - 9 + 3 * kz;
        bool zv = (unsigned)zi < (unsigned)S_;
        int zc2 = min(max(zi, 0), S_ - 1);
        #pragma unroll 1
        for (int ky = 0; ky < 7; ++ky) {
            int yi = y - 9 + 3 * ky;
            bool yv = (unsigned)yi < (unsigned)S_;
            int yc2 = min(max(yi, 0), S_ - 1);
            int abase = (zc2 * 400 + yc2 * 20) * 32 + c;
            int wbase = (kz * 49 + ky * 7) * 32 + c;
            #pragma unroll
            for (int kx = 0; kx < 7; ++kx) {
                int xi = xx - 9 + 3 * kx;
                bool xv = (unsigned)xi < (unsigned)S_;
                int xc2 = min(max(xi, 0), S_ - 1);
                float a = attn1T[abase + xc2 * 32];
                float w = wspT[wbase + kx * 32];
                acc += (zv && yv && xv) ? a * w : 0.f;
            }
        }
    }
    s_attn[vl][c] = acc + b_sp[c];
    __syncthreads();

    const int o = c;
    float acc2 = b_pw[o];
    #pragma unroll
    for (int cc = 0; cc < C_; ++cc)
        acc2 += wpwT[cc * 32 + o] * s_attn[vl][cc];
    out[o * V_ + v] = x[o * V_ + v] * acc2;
}

// ---------------------------------------------------------------------------
extern "C" void kernel_launch(void* const* d_in, const int* in_sizes, int n_in,
                              void* d_out, int out_size, void* d_ws, size_t ws_size,
                              hipStream_t stream)
{
    const float* x     = (const float*)d_in[0];
    const float* w_off = (const float*)d_in[1];
    const float* b_off = (const float*)d_in[2];
    const float* w_dw  = (const float*)d_in[3];
    const float* b_dw  = (const float*)d_in[4];
    const float* w_sp  = (const float*)d_in[5];
    const float* b_sp  = (const float*)d_in[6];
    const float* w_pw  = (const float*)d_in[7];
    const float* b_pw  = (const float*)d_in[8];
    float* ws = (float*)d_ws;
    float* out = (float*)d_out;

    unsigned short* xt    = (unsigned short*)(ws + WS_XT);
    unsigned short* offbT = (unsigned short*)(ws + WS_OFFB);
    unsigned short* Bprep = (unsigned short*)(ws + WS_BPREP);
    unsigned*       xp    = (unsigned*)(ws + WS_XP);

    hipLaunchKernelGGL(transpose_kernel, dim3((272016 + 255) / 256), dim3(256), 0, stream,
                       x, w_dw, w_sp, w_pw, xt,
                       ws + WS_WDWT, ws + WS_WSPT, ws + WS_WPWT, ws + WS_ZERO);

    hipLaunchKernelGGL(prep_b_kernel, dim3((NP_ * KK_ + 255) / 256), dim3(256), 0, stream,
                       w_off, Bprep);

    hipLaunchKernelGGL(gemm_off_kernel, dim3(125, 6), dim3(256), 0, stream,
                       xt, Bprep, b_off, ws + WS_ZERO, offbT);

    hipLaunchKernelGGL(pack_xp_kernel, dim3(1000), dim3(256), 0, stream,
                       xt, xp);

    hipLaunchKernelGGL(deform_kernel, dim3(1000), dim3(256), 0, stream,
                       xp, ws + WS_WDWT, b_dw, offbT, ws + WS_ATTN1T);

    hipLaunchKernelGGL(spatial_pw_kernel, dim3(1000), dim3(256), 0, stream,
                       ws + WS_WSPT, b_sp, ws + WS_ATTN1T,
                       ws + WS_WPWT, b_pw, x, out);
}